// Round 1
// baseline (165.969 us; speedup 1.0000x reference)
//
#include <hip/hip_runtime.h>
#include <math.h>

// Problem geometry (static per reference file):
//   x: [28, 256, 128, 128] fp32, groups lens = {4,3,4,4,3,4,2,4}, starts = prefix sums.
//   For group g (slab of L*256 rows of d=16384 floats, row r = c*L + k):
//     out[g, c', e] = sum_k softmax_k( dot(row_{c*L+q}, row_{c*L+k}) / 16 ) * row_{c*L+k}[e]
//   with c = c' / L, q = c' % L.

#define DIMD 16384   // 128*128
#define NCH  256

__global__ __launch_bounds__(256) void attfusion_kernel(const float* __restrict__ x,
                                                        float* __restrict__ out) {
    __shared__ float red[4][4];   // [wave][k] partial dot sums
    __shared__ float w_lds[4];    // softmax weights

    const int gid = blockIdx.x;        // 0 .. 8*256-1
    const int g   = gid >> 8;          // group index
    const int cp  = gid & 255;         // output row c' within group

    const int lens[8]   = {4, 3, 4, 4, 3, 4, 2, 4};
    const int starts[8] = {0, 4, 7, 11, 15, 18, 22, 24};
    const int L = lens[g];
    const int c = cp / L;
    const int q = cp - c * L;

    const float* base = x + (size_t)starts[g] * NCH * DIMD;   // group slab
    const float* rowq = base + (size_t)(c * L + q) * DIMD;

    const int tid  = threadIdx.x;
    const int lane = tid & 63;
    const int wave = tid >> 6;

    // ---- phase 1: partial dot products s_k = <row_q, row_k> ----
    float acc[4] = {0.f, 0.f, 0.f, 0.f};
    const float4* rowq4 = (const float4*)rowq;
    #pragma unroll
    for (int i = 0; i < 16; ++i) {
        const int e4 = i * 256 + tid;             // 4096 float4 per row
        float4 vq = rowq4[e4];
        for (int k = 0; k < L; ++k) {
            const float4* rk4 = (const float4*)(base + (size_t)(c * L + k) * DIMD);
            float4 vk = rk4[e4];
            acc[k] = fmaf(vq.x, vk.x, acc[k]);
            acc[k] = fmaf(vq.y, vk.y, acc[k]);
            acc[k] = fmaf(vq.z, vk.z, acc[k]);
            acc[k] = fmaf(vq.w, vk.w, acc[k]);
        }
    }

    // wave-level reduce (64 lanes), all 4 slots (k>=L are zeros, harmless)
    #pragma unroll
    for (int k = 0; k < 4; ++k) {
        float v = acc[k];
        #pragma unroll
        for (int off = 32; off > 0; off >>= 1) v += __shfl_down(v, off, 64);
        if (lane == 0) red[wave][k] = v;
    }
    __syncthreads();

    // cross-wave reduce + softmax on thread 0
    if (tid == 0) {
        float s[4];
        float m = -3.0e38f;
        for (int k = 0; k < L; ++k) {
            s[k] = (red[0][k] + red[1][k] + red[2][k] + red[3][k]) * 0.0625f; // /sqrt(256)
            m = fmaxf(m, s[k]);
        }
        float denom = 0.f;
        for (int k = 0; k < L; ++k) { s[k] = expf(s[k] - m); denom += s[k]; }
        float inv = 1.0f / denom;
        for (int k = 0; k < 4; ++k) w_lds[k] = (k < L) ? s[k] * inv : 0.f;
    }
    __syncthreads();

    float w0 = w_lds[0], w1 = w_lds[1], w2 = w_lds[2], w3 = w_lds[3];

    // ---- phase 2: out_row = sum_k w_k * row_k (rows are L2-warm from phase 1) ----
    float* orow = out + (size_t)gid * DIMD;
    const float4* r0 = (const float4*)(base + (size_t)(c * L + 0) * DIMD);
    const float4* r1 = (const float4*)(base + (size_t)(c * L + ((L > 1) ? 1 : 0)) * DIMD);
    const float4* r2 = (const float4*)(base + (size_t)(c * L + ((L > 2) ? 2 : 0)) * DIMD);
    const float4* r3 = (const float4*)(base + (size_t)(c * L + ((L > 3) ? 3 : 0)) * DIMD);

    #pragma unroll
    for (int i = 0; i < 16; ++i) {
        const int e4 = i * 256 + tid;
        float4 a = r0[e4];
        float4 b = r1[e4];
        float4 cc = r2[e4];
        float4 dd = r3[e4];
        float4 o;
        o.x = w0 * a.x + w1 * b.x + w2 * cc.x + w3 * dd.x;
        o.y = w0 * a.y + w1 * b.y + w2 * cc.y + w3 * dd.y;
        o.z = w0 * a.z + w1 * b.z + w2 * cc.z + w3 * dd.z;
        o.w = w0 * a.w + w1 * b.w + w2 * cc.w + w3 * dd.w;
        ((float4*)orow)[e4] = o;
    }
}

extern "C" void kernel_launch(void* const* d_in, const int* in_sizes, int n_in,
                              void* d_out, int out_size, void* d_ws, size_t ws_size,
                              hipStream_t stream) {
    const float* x = (const float*)d_in[0];
    float* out = (float*)d_out;
    // 8 groups * 256 output rows
    attfusion_kernel<<<dim3(8 * 256), dim3(256), 0, stream>>>(x, out);
}

// Round 2
// 70.309 us; speedup vs baseline: 2.3606x; 2.3606x over previous
//
#include <hip/hip_runtime.h>
#include <math.h>

// Geometry (static): x: [28, 256, 128, 128] fp32, group lens {4,3,4,4,3,4,2,4}.
// Reference reinterprets each group slab [L,256,16384] as [256, L, 16384]:
// "row r" = slab row r of 16384 floats, cluster c uses rows c*L..c*L+L-1.
// out[g, cp, :] with cp = c*L+q is softmax_k(dot(row_{cL+q},row_{cL+k})/16) @ rows.
// One block per (g,c) cluster: read L rows once -> full gram -> softmax for all
// q -> re-read L rows (L2-warm) -> write up to L output rows.

#define DIMD 16384   // 128*128
#define NCH  256

template <int L>
__device__ __forceinline__ void run_cluster(const float* __restrict__ base,
                                            float* __restrict__ outg,
                                            int c, int tid) {
    constexpr int NP = L * (L + 1) / 2;
    __shared__ float red[4][NP];
    __shared__ float w_lds[4][4];

    const int lane = tid & 63;
    const int wave = tid >> 6;

    const float4* rows[L];
    #pragma unroll
    for (int k = 0; k < L; ++k)
        rows[k] = (const float4*)(base + (size_t)(c * L + k) * DIMD);

    // ---- phase 1: gram matrix (pairs only) ----
    float accp[NP];
    #pragma unroll
    for (int p = 0; p < NP; ++p) accp[p] = 0.f;

    #pragma unroll
    for (int i = 0; i < 16; ++i) {
        const int e4 = i * 256 + tid;       // 4096 float4 per row
        float4 v[L];
        #pragma unroll
        for (int k = 0; k < L; ++k) v[k] = rows[k][e4];
        int idx = 0;
        #pragma unroll
        for (int a = 0; a < L; ++a) {
            #pragma unroll
            for (int b = a; b < L; ++b) {
                accp[idx] = fmaf(v[a].x, v[b].x, accp[idx]);
                accp[idx] = fmaf(v[a].y, v[b].y, accp[idx]);
                accp[idx] = fmaf(v[a].z, v[b].z, accp[idx]);
                accp[idx] = fmaf(v[a].w, v[b].w, accp[idx]);
                ++idx;
            }
        }
    }

    #pragma unroll
    for (int p = 0; p < NP; ++p) {
        float v = accp[p];
        #pragma unroll
        for (int off = 32; off > 0; off >>= 1) v += __shfl_down(v, off, 64);
        if (lane == 0) red[wave][p] = v;
    }
    __syncthreads();

    if (tid == 0) {
        float S[L][L];
        int idx = 0;
        for (int a = 0; a < L; ++a)
            for (int b = a; b < L; ++b) {
                float s = (red[0][idx] + red[1][idx] + red[2][idx] + red[3][idx]) * 0.0625f;
                S[a][b] = s; S[b][a] = s; ++idx;
            }
        for (int q = 0; q < L; ++q) {
            float m = S[q][0];
            for (int k = 1; k < L; ++k) m = fmaxf(m, S[q][k]);
            float e[L], denom = 0.f;
            for (int k = 0; k < L; ++k) { e[k] = expf(S[q][k] - m); denom += e[k]; }
            float inv = 1.0f / denom;
            for (int k = 0; k < L; ++k) w_lds[q][k] = e[k] * inv;
        }
    }
    __syncthreads();

    // ---- phase 2: weighted sums for all outputs of this cluster ----
    const int nout = min(L, NCH - c * L);   // partial tail cluster for L=3

    #pragma unroll
    for (int i = 0; i < 16; ++i) {
        const int e4 = i * 256 + tid;
        float4 v[L];
        #pragma unroll
        for (int k = 0; k < L; ++k) v[k] = rows[k][e4];
        for (int q = 0; q < nout; ++q) {
            float4 o = {0.f, 0.f, 0.f, 0.f};
            #pragma unroll
            for (int k = 0; k < L; ++k) {
                const float w = w_lds[q][k];
                o.x = fmaf(w, v[k].x, o.x);
                o.y = fmaf(w, v[k].y, o.y);
                o.z = fmaf(w, v[k].z, o.z);
                o.w = fmaf(w, v[k].w, o.w);
            }
            ((float4*)(outg + (size_t)(c * L + q) * DIMD))[e4] = o;
        }
    }
}

__global__ __launch_bounds__(256) void attfusion_cluster_kernel(const float* __restrict__ x,
                                                                float* __restrict__ out) {
    const int lens[8]   = {4, 3, 4, 4, 3, 4, 2, 4};
    const int starts[8] = {0, 4, 7, 11, 15, 18, 22, 24};
    // clusters per group: ceil(256/L) -> {64,86,64,64,86,64,128,64}, prefix:
    const int coff[9] = {0, 64, 150, 214, 278, 364, 428, 556, 620};

    const int b = blockIdx.x;
    int g = 0;
    while (b >= coff[g + 1]) ++g;   // uniform across block
    const int c = b - coff[g];

    const float* base = x + (size_t)starts[g] * NCH * DIMD;
    float* outg = out + (size_t)g * NCH * DIMD;
    const int L = lens[g];

    if (L == 4)      run_cluster<4>(base, outg, c, threadIdx.x);
    else if (L == 3) run_cluster<3>(base, outg, c, threadIdx.x);
    else             run_cluster<2>(base, outg, c, threadIdx.x);
}

extern "C" void kernel_launch(void* const* d_in, const int* in_sizes, int n_in,
                              void* d_out, int out_size, void* d_ws, size_t ws_size,
                              hipStream_t stream) {
    const float* x = (const float*)d_in[0];
    float* out = (float*)d_out;
    attfusion_cluster_kernel<<<dim3(620), dim3(256), 0, stream>>>(x, out);
}

// Round 3
// 67.908 us; speedup vs baseline: 2.4440x; 1.0354x over previous
//
#include <hip/hip_runtime.h>
#include <math.h>

// Geometry (static): x: [28, 256, 128, 128] fp32, group lens {4,3,4,4,3,4,2,4}.
// Group slab [L,256,16384] viewed as [256, L, 16384]: cluster c uses slab rows
// c*L..c*L+L-1 (16384 floats each). out[g, c*L+q, :] =
//   sum_k softmax_k(dot(row_q,row_k)/16) * row_k, for c*L+q < 256.
//
// Two-pass: A computes per-(cluster, d-chunk) partial gram sums into d_ws
// (no atomics, fully overwritten -> deterministic); B sums partials, does the
// (redundant, cheap) softmax, and streams the weighted sum out.

#define DIMD   16384   // floats per row
#define NCH    256
#define NCHUNK 8
#define CHUNK4 512     // float4 per chunk (2048 floats)
#define MAXNP  10
#define NCLUST 620
#define WS_FLOATS (NCLUST * NCHUNK * MAXNP)

__device__ __forceinline__ int group_of(int cluster, int& c) {
    const int coff[9] = {0, 64, 150, 214, 278, 364, 428, 556, 620};
    int g = 0;
    while (cluster >= coff[g + 1]) ++g;
    c = cluster - coff[g];
    return g;
}

// ---------------- Kernel A: partial gram ----------------
template <int L>
__device__ __forceinline__ void gram_partial(const float* __restrict__ base, int c, int chunk,
                                             float* __restrict__ outp, int tid) {
    constexpr int NP = L * (L + 1) / 2;
    __shared__ float red[4][NP];
    const int lane = tid & 63, wave = tid >> 6;

    const float4* rows[L];
    #pragma unroll
    for (int k = 0; k < L; ++k)
        rows[k] = (const float4*)(base + (size_t)(c * L + k) * DIMD) + chunk * CHUNK4;

    float acc[NP];
    #pragma unroll
    for (int p = 0; p < NP; ++p) acc[p] = 0.f;

    #pragma unroll
    for (int i = 0; i < 2; ++i) {
        const int e4 = i * 256 + tid;
        float4 v[L];
        #pragma unroll
        for (int k = 0; k < L; ++k) v[k] = rows[k][e4];
        int idx = 0;
        #pragma unroll
        for (int a = 0; a < L; ++a) {
            #pragma unroll
            for (int b = a; b < L; ++b) {
                acc[idx] = fmaf(v[a].x, v[b].x, acc[idx]);
                acc[idx] = fmaf(v[a].y, v[b].y, acc[idx]);
                acc[idx] = fmaf(v[a].z, v[b].z, acc[idx]);
                acc[idx] = fmaf(v[a].w, v[b].w, acc[idx]);
                ++idx;
            }
        }
    }

    #pragma unroll
    for (int p = 0; p < NP; ++p) {
        float v = acc[p];
        #pragma unroll
        for (int off = 32; off > 0; off >>= 1) v += __shfl_down(v, off, 64);
        if (lane == 0) red[wave][p] = v;
    }
    __syncthreads();
    if (tid < NP) outp[tid] = red[0][tid] + red[1][tid] + red[2][tid] + red[3][tid];
}

__global__ __launch_bounds__(256) void gram_kernel(const float* __restrict__ x,
                                                   float* __restrict__ ws) {
    const int lens[8]   = {4, 3, 4, 4, 3, 4, 2, 4};
    const int starts[8] = {0, 4, 7, 11, 15, 18, 22, 24};
    const int cluster = blockIdx.x >> 3;
    const int chunk   = blockIdx.x & 7;
    int c; const int g = group_of(cluster, c);
    const float* base = x + (size_t)starts[g] * NCH * DIMD;
    float* outp = ws + ((size_t)cluster * NCHUNK + chunk) * MAXNP;
    const int L = lens[g];
    if (L == 4)      gram_partial<4>(base, c, chunk, outp, threadIdx.x);
    else if (L == 3) gram_partial<3>(base, c, chunk, outp, threadIdx.x);
    else             gram_partial<2>(base, c, chunk, outp, threadIdx.x);
}

// ---------------- Kernel B: softmax + weighted sum ----------------
template <int L>
__device__ __forceinline__ void fuse_chunk(const float* __restrict__ base,
                                           float* __restrict__ outg,
                                           const float* __restrict__ wsc,
                                           int c, int chunk, int tid) {
    constexpr int NP = L * (L + 1) / 2;
    __shared__ float S_l[NP];
    __shared__ float w_lds[4][4];

    if (tid < NP) {
        float s = 0.f;
        #pragma unroll
        for (int ch = 0; ch < NCHUNK; ++ch) s += wsc[ch * MAXNP + tid];
        S_l[tid] = s * 0.0625f;   // 1/sqrt(256)
    }
    __syncthreads();
    if (tid == 0) {
        float S[L][L];
        int idx = 0;
        for (int a = 0; a < L; ++a)
            for (int b = a; b < L; ++b) { float s = S_l[idx]; S[a][b] = s; S[b][a] = s; ++idx; }
        for (int q = 0; q < L; ++q) {
            float m = S[q][0];
            for (int k = 1; k < L; ++k) m = fmaxf(m, S[q][k]);
            float e[L], den = 0.f;
            for (int k = 0; k < L; ++k) { e[k] = expf(S[q][k] - m); den += e[k]; }
            float inv = 1.0f / den;
            for (int k = 0; k < L; ++k) w_lds[q][k] = e[k] * inv;
        }
    }
    __syncthreads();

    const int nout = min(L, NCH - c * L);
    const float4* rows[L];
    #pragma unroll
    for (int k = 0; k < L; ++k)
        rows[k] = (const float4*)(base + (size_t)(c * L + k) * DIMD) + chunk * CHUNK4;

    #pragma unroll
    for (int i = 0; i < 2; ++i) {
        const int e4 = i * 256 + tid;
        float4 v[L];
        #pragma unroll
        for (int k = 0; k < L; ++k) v[k] = rows[k][e4];
        for (int q = 0; q < nout; ++q) {
            float4 o = {0.f, 0.f, 0.f, 0.f};
            #pragma unroll
            for (int k = 0; k < L; ++k) {
                const float w = w_lds[q][k];
                o.x = fmaf(w, v[k].x, o.x);
                o.y = fmaf(w, v[k].y, o.y);
                o.z = fmaf(w, v[k].z, o.z);
                o.w = fmaf(w, v[k].w, o.w);
            }
            ((float4*)(outg + (size_t)(c * L + q) * DIMD))[chunk * CHUNK4 + e4] = o;
        }
    }
}

__global__ __launch_bounds__(256) void fuse_kernel(const float* __restrict__ x,
                                                   const float* __restrict__ ws,
                                                   float* __restrict__ out) {
    const int lens[8]   = {4, 3, 4, 4, 3, 4, 2, 4};
    const int starts[8] = {0, 4, 7, 11, 15, 18, 22, 24};
    const int cluster = blockIdx.x >> 3;
    const int chunk   = blockIdx.x & 7;
    int c; const int g = group_of(cluster, c);
    const float* base = x + (size_t)starts[g] * NCH * DIMD;
    float* outg = out + (size_t)g * NCH * DIMD;
    const float* wsc = ws + (size_t)cluster * NCHUNK * MAXNP;
    const int L = lens[g];
    if (L == 4)      fuse_chunk<4>(base, outg, wsc, c, chunk, threadIdx.x);
    else if (L == 3) fuse_chunk<3>(base, outg, wsc, c, chunk, threadIdx.x);
    else             fuse_chunk<2>(base, outg, wsc, c, chunk, threadIdx.x);
}

extern "C" void kernel_launch(void* const* d_in, const int* in_sizes, int n_in,
                              void* d_out, int out_size, void* d_ws, size_t ws_size,
                              hipStream_t stream) {
    const float* x = (const float*)d_in[0];
    float* out = (float*)d_out;
    float* ws = (float*)d_ws;
    gram_kernel<<<dim3(NCLUST * NCHUNK), dim3(256), 0, stream>>>(x, ws);
    fuse_kernel<<<dim3(NCLUST * NCHUNK), dim3(256), 0, stream>>>(x, ws, out);
}